// Round 7
// baseline (174.296 us; speedup 1.0000x reference)
//
#include <hip/hip_runtime.h>
#include <math.h>

#define NCLUS 56
#define HH 224
#define WW 224
#define BB 32
#define CELLS (NCLUS * NCLUS) /* 3136 */
#define HW (HH * WW)

typedef float f32x4 __attribute__((ext_vector_type(4)));

// ---------------------------------------------------------------------------
// Kernel A: Sobel -> grad mag -> inverted -> 4x4 mean pool. (R4, unchanged)
// ---------------------------------------------------------------------------
__global__ __launch_bounds__(256) void pool_kernel(const float* __restrict__ cf,
                                                   float* __restrict__ pooled) {
    __shared__ float lds[18][226];
    int b = blockIdx.x / 14;
    int grp = blockIdx.x - b * 14;
    int tid = threadIdx.x;
    const float* e = cf + ((size_t)b * 65 + 64) * HW;

    int y0 = grp * 16 - 1;
    for (int t = tid; t < 18 * 224; t += 256) {
        int r = t / 224;
        int c = t - r * 224;
        int y = y0 + r;
        lds[r][c + 1] = (y >= 0 && y < HH) ? e[y * WW + c] : 0.0f;
    }
    if (tid < 18) { lds[tid][0] = 0.0f; lds[tid][225] = 0.0f; }
    __syncthreads();

    if (tid >= 224) return;
    int lby = tid / 56;
    int bx = tid - lby * 56;
    int r0 = lby * 4;
    int c0 = bx * 4;

    float patch[6][6];
#pragma unroll
    for (int i = 0; i < 6; ++i)
#pragma unroll
        for (int j = 0; j < 6; ++j) patch[i][j] = lds[r0 + i][c0 + j];

    float s = 0.0f;
#pragma unroll
    for (int iy = 0; iy < 4; ++iy) {
#pragma unroll
        for (int ix = 0; ix < 4; ++ix) {
            float gx = (patch[iy][ix + 2] - patch[iy][ix])
                     + 2.0f * (patch[iy + 1][ix + 2] - patch[iy + 1][ix])
                     + (patch[iy + 2][ix + 2] - patch[iy + 2][ix]);
            float gy = (patch[iy + 2][ix] - patch[iy][ix])
                     + 2.0f * (patch[iy + 2][ix + 1] - patch[iy][ix + 1])
                     + (patch[iy + 2][ix + 2] - patch[iy][ix + 2]);
            float gm = sqrtf(gx * gx + gy * gy);
            s += 1.0f - 0.5f * gm;
        }
    }
    pooled[b * CELLS + (grp * 4 + lby) * NCLUS + bx] = s * 0.0625f;
}

// ---------------------------------------------------------------------------
// Kernel B: per-batch top-56 via radix select + rank sort. (R4, unchanged)
// ---------------------------------------------------------------------------
__global__ __launch_bounds__(256) void topk_kernel(
        const float* __restrict__ pooled,
        float* __restrict__ sy, float* __restrict__ sx) {
    int b = blockIdx.x;
    int tid = threadIdx.x;
    __shared__ unsigned long long list[CELLS];
    __shared__ unsigned nlist_s;
    if (tid == 0) nlist_s = 0;

    if (tid < 64) {
        unsigned hi[49];
#pragma unroll
        for (int j = 0; j < 49; ++j) {
            int i = j * 64 + tid;
            unsigned u = __float_as_uint(pooled[b * CELLS + i]);
            hi[j] = (u & 0x80000000u) ? ~u : (u | 0x80000000u);
        }
        unsigned prefix = 0;
        unsigned cnt = CELLS;
        for (int bit = 31; bit >= 0; --bit) {
            if (cnt <= 448u) break;
            unsigned cand = prefix | (1u << bit);
            unsigned c = 0;
#pragma unroll
            for (int j = 0; j < 49; ++j) c += (hi[j] >= cand) ? 1u : 0u;
#pragma unroll
            for (int off = 32; off >= 1; off >>= 1)
                c += __shfl_xor(c, off, 64);
            if (c >= (unsigned)NCLUS) { prefix = cand; cnt = c; } // uniform
        }
#pragma unroll
        for (int j = 0; j < 49; ++j) {
            if (hi[j] >= prefix) {
                unsigned pos = atomicAdd(&nlist_s, 1u);
                unsigned i = (unsigned)(j * 64 + tid);
                list[pos] = ((unsigned long long)hi[j] << 32) |
                            (unsigned long long)(0xFFFFFFFFu - i);
            }
        }
    }
    __syncthreads();

    int N = (int)nlist_s;
    for (int c = tid; c < N; c += 256) {
        unsigned long long key = list[c];
        int r = 0;
        for (int j = 0; j < N; ++j) r += (list[j] > key) ? 1 : 0;
        if (r < NCLUS) {
            unsigned idx = 0xFFFFFFFFu - (unsigned)(key & 0xFFFFFFFFull);
            sy[b * NCLUS + r] = (float)(idx / NCLUS) / (float)NCLUS;
            sx[b * NCLUS + r] = (float)(idx % NCLUS) / (float)NCLUS;
        }
    }
}

// ---------------------------------------------------------------------------
// Kernel C: fused tables + factored softmax + NT stores. (R4, unchanged)
// PROBE: launched TWICE this round; dur_us delta vs round 4 = this kernel's
// standalone duration (second launch rewrites identical values).
// ---------------------------------------------------------------------------
__global__ __launch_bounds__(448) void markers_kernel(
        const float* __restrict__ sy, const float* __restrict__ sx,
        const float* __restrict__ stdp, float* __restrict__ out) {
    __shared__ float fx_lds[NCLUS][WW]; // 50,176 B
    __shared__ float fy_s[8 * NCLUS];   //  1,792 B
    int blk = blockIdx.x;
    int b = blk / 28;
    int h0 = (blk - b * 28) * 8;
    int tid = threadIdx.x;
    float inv_std = 1.0f / stdp[0];
    const float* syb = sy + b * NCLUS;
    const float* sxb = sx + b * NCLUS;

    for (int t = tid; t < NCLUS * WW; t += 448) {
        int k = t / WW;
        int w = t - k * WW;
        float tx = ((float)w / 224.0f - sxb[k]) * inv_std;
        fx_lds[k][w] = expf(0.5f * expf(-(tx * tx)));
    }
    {
        int row = tid / NCLUS;
        int k = tid - row * NCLUS;
        float ty = ((float)(h0 + row) / 224.0f - syb[k]) * inv_std;
        fy_s[tid] = expf(0.5f * expf(-(ty * ty)));
    }
    __syncthreads();

    int row = tid / 56;      // 0..7
    int wq = tid - row * 56; // 0..55 -> w = 4*wq
    const float* fyp = fy_s + row * NCLUS;

    float s0 = 0.f, s1 = 0.f, s2 = 0.f, s3 = 0.f;
#pragma unroll 8
    for (int k = 0; k < NCLUS; ++k) {
        float fy = fyp[k];
        f32x4 fx = *(const f32x4*)&fx_lds[k][wq * 4];
        s0 = fmaf(fy, fx.x, s0);
        s1 = fmaf(fy, fx.y, s1);
        s2 = fmaf(fy, fx.z, s2);
        s3 = fmaf(fy, fx.w, s3);
    }
    float r0 = 1.0f / s0, r1 = 1.0f / s1, r2 = 1.0f / s2, r3 = 1.0f / s3;

    float* op = out + (size_t)b * NCLUS * HW + (size_t)(h0 + row) * WW + wq * 4;
#pragma unroll 8
    for (int k = 0; k < NCLUS; ++k) {
        float fy = fyp[k];
        f32x4 fx = *(const f32x4*)&fx_lds[k][wq * 4];
        f32x4 o;
        o.x = (fy * fx.x) * r0;
        o.y = (fy * fx.y) * r1;
        o.z = (fy * fx.z) * r2;
        o.w = (fy * fx.w) * r3;
        __builtin_nontemporal_store(o, (f32x4*)op);
        op += HW;
    }
}

// ---------------------------------------------------------------------------
extern "C" void kernel_launch(void* const* d_in, const int* in_sizes, int n_in,
                              void* d_out, int out_size, void* d_ws,
                              size_t ws_size, hipStream_t stream) {
    const float* cf = (const float*)d_in[0];   // (32, 65, 224, 224) f32
    const float* stdp = (const float*)d_in[1]; // scalar f32
    float* out = (float*)d_out;                // (32, 56, 224, 224) f32

    char* ws = (char*)d_ws;
    float* pooled = (float*)ws;                    // 401 KB
    float* sy = (float*)(ws + 512 * 1024);         // 7 KB
    float* sx = (float*)(ws + 576 * 1024);         // 7 KB

    pool_kernel<<<BB * 14, 256, 0, stream>>>(cf, pooled);
    topk_kernel<<<BB, 256, 0, stream>>>(pooled, sy, sx);
    // PROBE: markers launched twice. Second launch writes identical values
    // (deterministic, reads only sy/sx/std); dur_us - 99.1 == markers time.
    markers_kernel<<<BB * 28, 448, 0, stream>>>(sy, sx, stdp, out);
    markers_kernel<<<BB * 28, 448, 0, stream>>>(sy, sx, stdp, out);
}

// Round 8
// 113.931 us; speedup vs baseline: 1.5298x; 1.5298x over previous
//
#include <hip/hip_runtime.h>
#include <math.h>

#define NCLUS 56
#define HH 224
#define WW 224
#define BB 32
#define CELLS (NCLUS * NCLUS) /* 3136 */
#define HW (HH * WW)

typedef float f32x4 __attribute__((ext_vector_type(4)));

// ---------------------------------------------------------------------------
// Kernel A: Sobel -> grad mag -> inverted -> 4x4 mean pool. (unchanged)
// ---------------------------------------------------------------------------
__global__ __launch_bounds__(256) void pool_kernel(const float* __restrict__ cf,
                                                   float* __restrict__ pooled) {
    __shared__ float lds[18][226];
    int b = blockIdx.x / 14;
    int grp = blockIdx.x - b * 14;
    int tid = threadIdx.x;
    const float* e = cf + ((size_t)b * 65 + 64) * HW;

    int y0 = grp * 16 - 1;
    for (int t = tid; t < 18 * 224; t += 256) {
        int r = t / 224;
        int c = t - r * 224;
        int y = y0 + r;
        lds[r][c + 1] = (y >= 0 && y < HH) ? e[y * WW + c] : 0.0f;
    }
    if (tid < 18) { lds[tid][0] = 0.0f; lds[tid][225] = 0.0f; }
    __syncthreads();

    if (tid >= 224) return;
    int lby = tid / 56;
    int bx = tid - lby * 56;
    int r0 = lby * 4;
    int c0 = bx * 4;

    float patch[6][6];
#pragma unroll
    for (int i = 0; i < 6; ++i)
#pragma unroll
        for (int j = 0; j < 6; ++j) patch[i][j] = lds[r0 + i][c0 + j];

    float s = 0.0f;
#pragma unroll
    for (int iy = 0; iy < 4; ++iy) {
#pragma unroll
        for (int ix = 0; ix < 4; ++ix) {
            float gx = (patch[iy][ix + 2] - patch[iy][ix])
                     + 2.0f * (patch[iy + 1][ix + 2] - patch[iy + 1][ix])
                     + (patch[iy + 2][ix + 2] - patch[iy + 2][ix]);
            float gy = (patch[iy + 2][ix] - patch[iy][ix])
                     + 2.0f * (patch[iy + 2][ix + 1] - patch[iy][ix + 1])
                     + (patch[iy + 2][ix + 2] - patch[iy][ix + 2]);
            float gm = sqrtf(gx * gx + gy * gy);
            s += 1.0f - 0.5f * gm;
        }
    }
    pooled[b * CELLS + (grp * 4 + lby) * NCLUS + bx] = s * 0.0625f;
}

// ---------------------------------------------------------------------------
// Kernel B: per-batch top-56 (radix select + rank sort, exact jax order)
// + Fx/Fy table generation. Tables move ALL transcendentals out of the
// write-bound kernel: Fx[b][k][w], Fy[b][h][k], fp32, 1.6MB each.
// ---------------------------------------------------------------------------
__global__ __launch_bounds__(256) void topk_tables_kernel(
        const float* __restrict__ pooled, const float* __restrict__ stdp,
        float* __restrict__ Fx, float* __restrict__ Fy) {
    int b = blockIdx.x;
    int tid = threadIdx.x;
    __shared__ unsigned long long list[CELLS];
    __shared__ float sy_s[NCLUS], sx_s[NCLUS];
    __shared__ unsigned nlist_s;
    if (tid == 0) nlist_s = 0;

    if (tid < 64) {
        unsigned hi[49];
#pragma unroll
        for (int j = 0; j < 49; ++j) {
            int i = j * 64 + tid;
            unsigned u = __float_as_uint(pooled[b * CELLS + i]);
            hi[j] = (u & 0x80000000u) ? ~u : (u | 0x80000000u);
        }
        unsigned prefix = 0;
        unsigned cnt = CELLS;
        for (int bit = 31; bit >= 0; --bit) {
            if (cnt <= 448u) break;
            unsigned cand = prefix | (1u << bit);
            unsigned c = 0;
#pragma unroll
            for (int j = 0; j < 49; ++j) c += (hi[j] >= cand) ? 1u : 0u;
#pragma unroll
            for (int off = 32; off >= 1; off >>= 1)
                c += __shfl_xor(c, off, 64);
            if (c >= (unsigned)NCLUS) { prefix = cand; cnt = c; } // uniform
        }
#pragma unroll
        for (int j = 0; j < 49; ++j) {
            if (hi[j] >= prefix) {
                unsigned pos = atomicAdd(&nlist_s, 1u);
                unsigned i = (unsigned)(j * 64 + tid);
                list[pos] = ((unsigned long long)hi[j] << 32) |
                            (unsigned long long)(0xFFFFFFFFu - i);
            }
        }
    }
    __syncthreads();

    int N = (int)nlist_s;
    for (int c = tid; c < N; c += 256) {
        unsigned long long key = list[c];
        int r = 0;
        for (int j = 0; j < N; ++j) r += (list[j] > key) ? 1 : 0;
        if (r < NCLUS) {
            unsigned idx = 0xFFFFFFFFu - (unsigned)(key & 0xFFFFFFFFull);
            sy_s[r] = (float)(idx / NCLUS) / (float)NCLUS;
            sx_s[r] = (float)(idx % NCLUS) / (float)NCLUS;
        }
    }
    __syncthreads();

    float inv_std = 1.0f / stdp[0];
    // Fx[b][k][w] (w contiguous)
    for (int t = tid; t < NCLUS * WW; t += 256) {
        int k = t / WW;
        int w = t - k * WW;
        float tx = ((float)w / 224.0f - sx_s[k]) * inv_std;
        Fx[(size_t)b * NCLUS * WW + t] = expf(0.5f * expf(-(tx * tx)));
    }
    // Fy[b][h][k] (k contiguous)
    for (int t = tid; t < HH * NCLUS; t += 256) {
        int h = t / NCLUS;
        int k = t - h * NCLUS;
        float ty = ((float)h / 224.0f - sy_s[k]) * inv_std;
        Fy[(size_t)b * HH * NCLUS + t] = expf(0.5f * expf(-(ty * ty)));
    }
}

// ---------------------------------------------------------------------------
// Kernel C: factored softmax + NT stores. 512 blocks (exactly 2/CU, ZERO
// residency tail) x 448 threads, 14 rows each. No transcendentals: tables
// copied global->LDS (53KB, L2-served, ~1us). 784 quads/block = 1.75/thread;
// the two quad iterations are independent so quad-1 sum work overlaps
// quad-0 store drain (fire-and-forget NT stores).
// ---------------------------------------------------------------------------
__global__ __launch_bounds__(448) void markers_kernel(
        const float* __restrict__ Fx, const float* __restrict__ Fy,
        float* __restrict__ out) {
    __shared__ float fx_lds[NCLUS][WW]; // 50,176 B
    __shared__ float fy_s[14 * NCLUS];  //  3,136 B
    int blk = blockIdx.x;
    int b = blk / 16;               // 16 blocks per batch
    int h0 = (blk - b * 16) * 14;   // 14 rows per block
    int tid = threadIdx.x;

    // stage tables
    const f32x4* fxg = (const f32x4*)(Fx + (size_t)b * NCLUS * WW);
    f32x4* fxl = (f32x4*)&fx_lds[0][0];
    for (int t = tid; t < NCLUS * WW / 4; t += 448) fxl[t] = fxg[t];
    const float* fyg = Fy + ((size_t)b * HH + h0) * NCLUS;
    for (int t = tid; t < 14 * NCLUS; t += 448) fy_s[t] = fyg[t];
    __syncthreads();

#pragma unroll
    for (int q = 0; q < 2; ++q) {
        int e = q * 448 + tid; // quad id in block, 0..783
        if (e < 14 * 56) {
            int row = e / 56;
            int wq = e - row * 56;
            const float* fyp = fy_s + row * NCLUS;

            float s0 = 0.f, s1 = 0.f, s2 = 0.f, s3 = 0.f;
#pragma unroll 8
            for (int k = 0; k < NCLUS; ++k) {
                float fy = fyp[k];
                f32x4 fx = *(const f32x4*)&fx_lds[k][wq * 4];
                s0 = fmaf(fy, fx.x, s0);
                s1 = fmaf(fy, fx.y, s1);
                s2 = fmaf(fy, fx.z, s2);
                s3 = fmaf(fy, fx.w, s3);
            }
            float r0 = 1.0f / s0, r1 = 1.0f / s1, r2 = 1.0f / s2,
                  r3 = 1.0f / s3;

            float* op = out + (size_t)b * NCLUS * HW +
                        (size_t)(h0 + row) * WW + wq * 4;
#pragma unroll 8
            for (int k = 0; k < NCLUS; ++k) {
                float fy = fyp[k];
                f32x4 fx = *(const f32x4*)&fx_lds[k][wq * 4];
                f32x4 o;
                o.x = (fy * fx.x) * r0;
                o.y = (fy * fx.y) * r1;
                o.z = (fy * fx.z) * r2;
                o.w = (fy * fx.w) * r3;
                __builtin_nontemporal_store(o, (f32x4*)op);
                op += HW;
            }
        }
    }
}

// ---------------------------------------------------------------------------
extern "C" void kernel_launch(void* const* d_in, const int* in_sizes, int n_in,
                              void* d_out, int out_size, void* d_ws,
                              size_t ws_size, hipStream_t stream) {
    const float* cf = (const float*)d_in[0];   // (32, 65, 224, 224) f32
    const float* stdp = (const float*)d_in[1]; // scalar f32
    float* out = (float*)d_out;                // (32, 56, 224, 224) f32

    char* ws = (char*)d_ws;
    float* pooled = (float*)ws;                       // 401 KB
    float* Fx = (float*)(ws + 512 * 1024);            // 1.6 MB
    float* Fy = (float*)(ws + 512 * 1024 + 2 * 1024 * 1024); // 1.6 MB

    pool_kernel<<<BB * 14, 256, 0, stream>>>(cf, pooled);
    topk_tables_kernel<<<BB, 256, 0, stream>>>(pooled, stdp, Fx, Fy);
    markers_kernel<<<512, 448, 0, stream>>>(Fx, Fy, out);
}

// Round 9
// 112.993 us; speedup vs baseline: 1.5425x; 1.0083x over previous
//
#include <hip/hip_runtime.h>
#include <math.h>

#define NCLUS 56
#define HH 224
#define WW 224
#define BB 32
#define CELLS (NCLUS * NCLUS) /* 3136 */
#define HW (HH * WW)

typedef float f32x4 __attribute__((ext_vector_type(4)));

// ---------------------------------------------------------------------------
// Kernel A: Sobel -> grad mag -> inverted -> 4x4 mean pool. (unchanged)
// ---------------------------------------------------------------------------
__global__ __launch_bounds__(256) void pool_kernel(const float* __restrict__ cf,
                                                   float* __restrict__ pooled) {
    __shared__ float lds[18][226];
    int b = blockIdx.x / 14;
    int grp = blockIdx.x - b * 14;
    int tid = threadIdx.x;
    const float* e = cf + ((size_t)b * 65 + 64) * HW;

    int y0 = grp * 16 - 1;
    for (int t = tid; t < 18 * 224; t += 256) {
        int r = t / 224;
        int c = t - r * 224;
        int y = y0 + r;
        lds[r][c + 1] = (y >= 0 && y < HH) ? e[y * WW + c] : 0.0f;
    }
    if (tid < 18) { lds[tid][0] = 0.0f; lds[tid][225] = 0.0f; }
    __syncthreads();

    if (tid >= 224) return;
    int lby = tid / 56;
    int bx = tid - lby * 56;
    int r0 = lby * 4;
    int c0 = bx * 4;

    float patch[6][6];
#pragma unroll
    for (int i = 0; i < 6; ++i)
#pragma unroll
        for (int j = 0; j < 6; ++j) patch[i][j] = lds[r0 + i][c0 + j];

    float s = 0.0f;
#pragma unroll
    for (int iy = 0; iy < 4; ++iy) {
#pragma unroll
        for (int ix = 0; ix < 4; ++ix) {
            float gx = (patch[iy][ix + 2] - patch[iy][ix])
                     + 2.0f * (patch[iy + 1][ix + 2] - patch[iy + 1][ix])
                     + (patch[iy + 2][ix + 2] - patch[iy + 2][ix]);
            float gy = (patch[iy + 2][ix] - patch[iy][ix])
                     + 2.0f * (patch[iy + 2][ix + 1] - patch[iy][ix + 1])
                     + (patch[iy + 2][ix + 2] - patch[iy][ix + 2]);
            float gm = sqrtf(gx * gx + gy * gy);
            s += 1.0f - 0.5f * gm;
        }
    }
    pooled[b * CELLS + (grp * 4 + lby) * NCLUS + bx] = s * 0.0625f;
}

// ---------------------------------------------------------------------------
// Kernel B: per-batch top-56 (radix select + rank sort, exact jax order)
// + Fx/Fy table generation (fp32, 1.6MB each, L2-resident). (R8, unchanged)
// ---------------------------------------------------------------------------
__global__ __launch_bounds__(256) void topk_tables_kernel(
        const float* __restrict__ pooled, const float* __restrict__ stdp,
        float* __restrict__ Fx, float* __restrict__ Fy) {
    int b = blockIdx.x;
    int tid = threadIdx.x;
    __shared__ unsigned long long list[CELLS];
    __shared__ float sy_s[NCLUS], sx_s[NCLUS];
    __shared__ unsigned nlist_s;
    if (tid == 0) nlist_s = 0;

    if (tid < 64) {
        unsigned hi[49];
#pragma unroll
        for (int j = 0; j < 49; ++j) {
            int i = j * 64 + tid;
            unsigned u = __float_as_uint(pooled[b * CELLS + i]);
            hi[j] = (u & 0x80000000u) ? ~u : (u | 0x80000000u);
        }
        unsigned prefix = 0;
        unsigned cnt = CELLS;
        for (int bit = 31; bit >= 0; --bit) {
            if (cnt <= 448u) break;
            unsigned cand = prefix | (1u << bit);
            unsigned c = 0;
#pragma unroll
            for (int j = 0; j < 49; ++j) c += (hi[j] >= cand) ? 1u : 0u;
#pragma unroll
            for (int off = 32; off >= 1; off >>= 1)
                c += __shfl_xor(c, off, 64);
            if (c >= (unsigned)NCLUS) { prefix = cand; cnt = c; } // uniform
        }
#pragma unroll
        for (int j = 0; j < 49; ++j) {
            if (hi[j] >= prefix) {
                unsigned pos = atomicAdd(&nlist_s, 1u);
                unsigned i = (unsigned)(j * 64 + tid);
                list[pos] = ((unsigned long long)hi[j] << 32) |
                            (unsigned long long)(0xFFFFFFFFu - i);
            }
        }
    }
    __syncthreads();

    int N = (int)nlist_s;
    for (int c = tid; c < N; c += 256) {
        unsigned long long key = list[c];
        int r = 0;
        for (int j = 0; j < N; ++j) r += (list[j] > key) ? 1 : 0;
        if (r < NCLUS) {
            unsigned idx = 0xFFFFFFFFu - (unsigned)(key & 0xFFFFFFFFull);
            sy_s[r] = (float)(idx / NCLUS) / (float)NCLUS;
            sx_s[r] = (float)(idx % NCLUS) / (float)NCLUS;
        }
    }
    __syncthreads();

    float inv_std = 1.0f / stdp[0];
    // Fx[b][k][w] (w contiguous)
    for (int t = tid; t < NCLUS * WW; t += 256) {
        int k = t / WW;
        int w = t - k * WW;
        float tx = ((float)w / 224.0f - sx_s[k]) * inv_std;
        Fx[(size_t)b * NCLUS * WW + t] = expf(0.5f * expf(-(tx * tx)));
    }
    // Fy[b][h][k] (k contiguous)
    for (int t = tid; t < HH * NCLUS; t += 256) {
        int h = t / NCLUS;
        int k = t - h * NCLUS;
        float ty = ((float)h / 224.0f - sy_s[k]) * inv_std;
        Fy[(size_t)b * HH * NCLUS + t] = expf(0.5f * expf(-(ty * ty)));
    }
}

// ---------------------------------------------------------------------------
// Kernel C: factored softmax, NO fx LDS table (fx read per-k from L2: 3.2MB
// table working set, re-read ~718MB logical at ~7TB/s -- far under the 34TB/s
// L2 ceiling). Only fy staged in LDS (1.8KB) -> all 896 blocks co-resident
// (~24.5 waves/CU vs R4's 21 in 3.5 rounds, R8's 14), zero tail rounds, and
// the storeless prologue shrinks from ~8us (table build + exps) to ~1-2us
// (one quad's 56 pipelined L2 loads). One quad per thread exactly.
// NT stores keep the 360MB stream from evicting the tables.
// ---------------------------------------------------------------------------
__global__ __launch_bounds__(448, 7) void markers_kernel(
        const float* __restrict__ Fx, const float* __restrict__ Fy,
        float* __restrict__ out) {
    __shared__ float fy_s[8 * NCLUS]; // 1,792 B
    int blk = blockIdx.x;
    int b = blk / 28;               // 28 blocks per batch
    int h0 = (blk - b * 28) * 8;    // 8 rows per block
    int tid = threadIdx.x;

    // fy staging: 448 contiguous floats, one per thread.
    fy_s[tid] = Fy[((size_t)b * HH + h0) * NCLUS + tid];
    __syncthreads();

    int row = tid / 56;      // 0..7
    int wq = tid - row * 56; // 0..55 -> w = 4*wq
    const float* fyp = fy_s + row * NCLUS;
    const f32x4* fxp = (const f32x4*)(Fx + (size_t)b * NCLUS * WW) + wq;

    float s0 = 0.f, s1 = 0.f, s2 = 0.f, s3 = 0.f;
#pragma unroll 8
    for (int k = 0; k < NCLUS; ++k) {
        float fy = fyp[k];
        f32x4 fx = fxp[(size_t)k * 56];
        s0 = fmaf(fy, fx.x, s0);
        s1 = fmaf(fy, fx.y, s1);
        s2 = fmaf(fy, fx.z, s2);
        s3 = fmaf(fy, fx.w, s3);
    }
    float r0 = 1.0f / s0, r1 = 1.0f / s1, r2 = 1.0f / s2, r3 = 1.0f / s3;

    float* op = out + (size_t)b * NCLUS * HW + (size_t)(h0 + row) * WW + wq * 4;
#pragma unroll 8
    for (int k = 0; k < NCLUS; ++k) {
        float fy = fyp[k];
        f32x4 fx = fxp[(size_t)k * 56];
        f32x4 o;
        o.x = (fy * fx.x) * r0;
        o.y = (fy * fx.y) * r1;
        o.z = (fy * fx.z) * r2;
        o.w = (fy * fx.w) * r3;
        __builtin_nontemporal_store(o, (f32x4*)op);
        op += HW;
    }
}

// ---------------------------------------------------------------------------
extern "C" void kernel_launch(void* const* d_in, const int* in_sizes, int n_in,
                              void* d_out, int out_size, void* d_ws,
                              size_t ws_size, hipStream_t stream) {
    const float* cf = (const float*)d_in[0];   // (32, 65, 224, 224) f32
    const float* stdp = (const float*)d_in[1]; // scalar f32
    float* out = (float*)d_out;                // (32, 56, 224, 224) f32

    char* ws = (char*)d_ws;
    float* pooled = (float*)ws;                              // 401 KB
    float* Fx = (float*)(ws + 512 * 1024);                   // 1.6 MB
    float* Fy = (float*)(ws + 512 * 1024 + 2 * 1024 * 1024); // 1.6 MB

    pool_kernel<<<BB * 14, 256, 0, stream>>>(cf, pooled);
    topk_tables_kernel<<<BB, 256, 0, stream>>>(pooled, stdp, Fx, Fy);
    markers_kernel<<<BB * 28, 448, 0, stream>>>(Fx, Fy, out);
}

// Round 10
// 103.713 us; speedup vs baseline: 1.6806x; 1.0895x over previous
//
#include <hip/hip_runtime.h>
#include <math.h>

#define NCLUS 56
#define HH 224
#define WW 224
#define BB 32
#define CELLS (NCLUS * NCLUS) /* 3136 */
#define HW (HH * WW)

typedef float f32x4 __attribute__((ext_vector_type(4)));

// ---------------------------------------------------------------------------
// Kernel A: Sobel -> grad mag -> inverted -> 4x4 mean pool. (R4, unchanged)
// ---------------------------------------------------------------------------
__global__ __launch_bounds__(256) void pool_kernel(const float* __restrict__ cf,
                                                   float* __restrict__ pooled) {
    __shared__ float lds[18][226];
    int b = blockIdx.x / 14;
    int grp = blockIdx.x - b * 14;
    int tid = threadIdx.x;
    const float* e = cf + ((size_t)b * 65 + 64) * HW;

    int y0 = grp * 16 - 1;
    for (int t = tid; t < 18 * 224; t += 256) {
        int r = t / 224;
        int c = t - r * 224;
        int y = y0 + r;
        lds[r][c + 1] = (y >= 0 && y < HH) ? e[y * WW + c] : 0.0f;
    }
    if (tid < 18) { lds[tid][0] = 0.0f; lds[tid][225] = 0.0f; }
    __syncthreads();

    if (tid >= 224) return;
    int lby = tid / 56;
    int bx = tid - lby * 56;
    int r0 = lby * 4;
    int c0 = bx * 4;

    float patch[6][6];
#pragma unroll
    for (int i = 0; i < 6; ++i)
#pragma unroll
        for (int j = 0; j < 6; ++j) patch[i][j] = lds[r0 + i][c0 + j];

    float s = 0.0f;
#pragma unroll
    for (int iy = 0; iy < 4; ++iy) {
#pragma unroll
        for (int ix = 0; ix < 4; ++ix) {
            float gx = (patch[iy][ix + 2] - patch[iy][ix])
                     + 2.0f * (patch[iy + 1][ix + 2] - patch[iy + 1][ix])
                     + (patch[iy + 2][ix + 2] - patch[iy + 2][ix]);
            float gy = (patch[iy + 2][ix] - patch[iy][ix])
                     + 2.0f * (patch[iy + 2][ix + 1] - patch[iy][ix + 1])
                     + (patch[iy + 2][ix + 2] - patch[iy][ix + 2]);
            float gm = sqrtf(gx * gx + gy * gy);
            s += 1.0f - 0.5f * gm;
        }
    }
    pooled[b * CELLS + (grp * 4 + lby) * NCLUS + bx] = s * 0.0625f;
}

// ---------------------------------------------------------------------------
// Kernel B: per-batch top-56 via radix select + rank sort. (R4, with the
// radix descent deepened: stop at <=128 candidates instead of <=448 so the
// O(N^2) rank pass drops ~3.5us -> ~1us; adds ~2 cheap bit rounds.)
// ---------------------------------------------------------------------------
__global__ __launch_bounds__(256) void topk_kernel(
        const float* __restrict__ pooled,
        float* __restrict__ sy, float* __restrict__ sx) {
    int b = blockIdx.x;
    int tid = threadIdx.x;
    __shared__ unsigned long long list[CELLS];
    __shared__ unsigned nlist_s;
    if (tid == 0) nlist_s = 0;

    if (tid < 64) {
        unsigned hi[49];
#pragma unroll
        for (int j = 0; j < 49; ++j) {
            int i = j * 64 + tid;
            unsigned u = __float_as_uint(pooled[b * CELLS + i]);
            hi[j] = (u & 0x80000000u) ? ~u : (u | 0x80000000u);
        }
        unsigned prefix = 0;
        unsigned cnt = CELLS;
        for (int bit = 31; bit >= 0; --bit) {
            if (cnt <= 128u) break;
            unsigned cand = prefix | (1u << bit);
            unsigned c = 0;
#pragma unroll
            for (int j = 0; j < 49; ++j) c += (hi[j] >= cand) ? 1u : 0u;
#pragma unroll
            for (int off = 32; off >= 1; off >>= 1)
                c += __shfl_xor(c, off, 64);
            if (c >= (unsigned)NCLUS) { prefix = cand; cnt = c; } // uniform
        }
#pragma unroll
        for (int j = 0; j < 49; ++j) {
            if (hi[j] >= prefix) {
                unsigned pos = atomicAdd(&nlist_s, 1u);
                unsigned i = (unsigned)(j * 64 + tid);
                list[pos] = ((unsigned long long)hi[j] << 32) |
                            (unsigned long long)(0xFFFFFFFFu - i);
            }
        }
    }
    __syncthreads();

    int N = (int)nlist_s;
    for (int c = tid; c < N; c += 256) {
        unsigned long long key = list[c];
        int r = 0;
        for (int j = 0; j < N; ++j) r += (list[j] > key) ? 1 : 0;
        if (r < NCLUS) {
            unsigned idx = 0xFFFFFFFFu - (unsigned)(key & 0xFFFFFFFFull);
            sy[b * NCLUS + r] = (float)(idx / NCLUS) / (float)NCLUS;
            sx[b * NCLUS + r] = (float)(idx % NCLUS) / (float)NCLUS;
        }
    }
}

// ---------------------------------------------------------------------------
// Kernel C: fused tables + factored softmax. EXACT R4 winning structure
// (75us standalone, measured R7): fp32 fx table in LDS, expf prologue,
// 448 threads / 8 rows / 896 blocks / 3 blocks/CU. SINGLE CHANGE: plain
// stores instead of __builtin_nontemporal_store -- the one untested toggle.
// Theory: NT bypasses L2 write-combining; plain write-back through the 32MB
// L2 is the path the 6.9TB/s fill uses.
// ---------------------------------------------------------------------------
__global__ __launch_bounds__(448) void markers_kernel(
        const float* __restrict__ sy, const float* __restrict__ sx,
        const float* __restrict__ stdp, float* __restrict__ out) {
    __shared__ float fx_lds[NCLUS][WW]; // 50,176 B
    __shared__ float fy_s[8 * NCLUS];   //  1,792 B
    int blk = blockIdx.x;
    int b = blk / 28;
    int h0 = (blk - b * 28) * 8;
    int tid = threadIdx.x;
    float inv_std = 1.0f / stdp[0];
    const float* syb = sy + b * NCLUS;
    const float* sxb = sx + b * NCLUS;

    for (int t = tid; t < NCLUS * WW; t += 448) {
        int k = t / WW;
        int w = t - k * WW;
        float tx = ((float)w / 224.0f - sxb[k]) * inv_std;
        fx_lds[k][w] = expf(0.5f * expf(-(tx * tx)));
    }
    {
        int row = tid / NCLUS;
        int k = tid - row * NCLUS;
        float ty = ((float)(h0 + row) / 224.0f - syb[k]) * inv_std;
        fy_s[tid] = expf(0.5f * expf(-(ty * ty)));
    }
    __syncthreads();

    int row = tid / 56;      // 0..7
    int wq = tid - row * 56; // 0..55 -> w = 4*wq
    const float* fyp = fy_s + row * NCLUS;

    float s0 = 0.f, s1 = 0.f, s2 = 0.f, s3 = 0.f;
#pragma unroll 8
    for (int k = 0; k < NCLUS; ++k) {
        float fy = fyp[k];
        f32x4 fx = *(const f32x4*)&fx_lds[k][wq * 4];
        s0 = fmaf(fy, fx.x, s0);
        s1 = fmaf(fy, fx.y, s1);
        s2 = fmaf(fy, fx.z, s2);
        s3 = fmaf(fy, fx.w, s3);
    }
    float r0 = 1.0f / s0, r1 = 1.0f / s1, r2 = 1.0f / s2, r3 = 1.0f / s3;

    float* op = out + (size_t)b * NCLUS * HW + (size_t)(h0 + row) * WW + wq * 4;
#pragma unroll 8
    for (int k = 0; k < NCLUS; ++k) {
        float fy = fyp[k];
        f32x4 fx = *(const f32x4*)&fx_lds[k][wq * 4];
        f32x4 o;
        o.x = (fy * fx.x) * r0;
        o.y = (fy * fx.y) * r1;
        o.z = (fy * fx.z) * r2;
        o.w = (fy * fx.w) * r3;
        *(f32x4*)op = o;   // PLAIN store (was NT) -- the A/B
        op += HW;
    }
}

// ---------------------------------------------------------------------------
extern "C" void kernel_launch(void* const* d_in, const int* in_sizes, int n_in,
                              void* d_out, int out_size, void* d_ws,
                              size_t ws_size, hipStream_t stream) {
    const float* cf = (const float*)d_in[0];   // (32, 65, 224, 224) f32
    const float* stdp = (const float*)d_in[1]; // scalar f32
    float* out = (float*)d_out;                // (32, 56, 224, 224) f32

    char* ws = (char*)d_ws;
    float* pooled = (float*)ws;                    // 401 KB
    float* sy = (float*)(ws + 512 * 1024);         // 7 KB
    float* sx = (float*)(ws + 576 * 1024);         // 7 KB

    pool_kernel<<<BB * 14, 256, 0, stream>>>(cf, pooled);
    topk_kernel<<<BB, 256, 0, stream>>>(pooled, sy, sx);
    markers_kernel<<<BB * 28, 448, 0, stream>>>(sy, sx, stdp, out);
}